// Round 18
// baseline (170.454 us; speedup 1.0000x reference)
//
#include <hip/hip_runtime.h>

// Problem: B=4, H=8, S=2048, D=64
// out  = [B*H*S*D]  floats   (first 4,194,304 of d_out)
// p    = [B*H*S*S]  floats   (next 134,217,728 of d_out)
#define NB 4
#define NH 8
#define NS 2048
#define ND 64
#define NBH (NB * NH)

typedef float f32x4  __attribute__((ext_vector_type(4)));
typedef float f32x16 __attribute__((ext_vector_type(16)));
typedef short s16x8  __attribute__((ext_vector_type(8)));
typedef unsigned int u32;

constexpr int TQ = 128;   // q rows per block
constexpr int TK = 128;   // keys per tile
constexpr int NT = NS / TK;
constexpr int ZHEADS = 8; // heads whose p-rows are zeroed by prep (134.2 MB)

// workspace layout
constexpr size_t PM_BYTES  = (size_t)NB * NS * (NS / 8);        // 2 MiB tile-major mask
constexpr size_t WSL_BYTES = 1 << 20;                           // 1 MiB row list
constexpr size_t KHL_OFF   = PM_BYTES + WSL_BYTES;
constexpr size_t KHL_BYTES = (size_t)NBH * NT * 32768;          // 16.78 MB hi+lo tiles
constexpr size_t QHI_OFF   = KHL_OFF + KHL_BYTES;
constexpr size_t QP_BYTES  = (size_t)NBH * NS * ND * 2;         // 8.39 MB per plane
constexpr size_t QLO_OFF   = QHI_OFF + QP_BYTES;
constexpr size_t REC_OFF   = QLO_OFF + QP_BYTES;
constexpr size_t REC4_BYTES= (size_t)NBH * NS * 4 * 16;         // 4 MB (NZ=4)
constexpr size_t REC2_BYTES= (size_t)NBH * NS * 2 * 16;         // 2 MB (NZ=2)
constexpr size_t WS_NEED4  = REC_OFF + REC4_BYTES;              // ~40.7 MB
constexpr size_t WS_NEED2  = REC_OFF + REC2_BYTES;              // ~38.7 MB

// f32 -> bf16 RNE bits
__device__ __forceinline__ u32 bf16_rne(u32 u) {
    return (u + 0x7FFFu + ((u >> 16) & 1u)) >> 16;
}
__device__ __forceinline__ void cvt_split(float x, u32 &hi, u32 &lo) {
    u32 h = bf16_rne(__float_as_uint(x));
    float hf = __uint_as_float(h << 16);
    lo = bf16_rne(__float_as_uint(x - hf));
    hi = h;
}

// ---------------------------------------------------------------------------
// prep: fused {mask pack, K split, Q split, wsl reset, PARTIAL p ZERO-FILL}.
// New vs r17: 2048 extra blocks (bid >= 6144) zero the first 134.2 MB of p
// (= all rows of heads 0..7) on prep's otherwise-idle write channel. prep is
// read-bound (84 MB mask+K+Q); HBM read/write streams overlap, so these
// stores are nearly free here and shave 25% off qk's store load.
// ---------------------------------------------------------------------------
__global__ __launch_bounds__(256)
void prep_kernel(const int* __restrict__ mask, u32* __restrict__ pmT,
                 const float* __restrict__ K, short* __restrict__ khl,
                 const float* __restrict__ Q, short* __restrict__ qhi,
                 short* __restrict__ qlo, int* __restrict__ wsl,
                 float* __restrict__ p)
{
    const int bid = blockIdx.x;
    if (bid == 0 && threadIdx.x == 0) wsl[0] = 0;

    if (bid < 2048) {
        // ---- tile-major packed mask: word idx = ((b*16+kt)*2048+q)*4+ks ----
        int idx = bid * 256 + threadIdx.x;
        int ks = idx & 3;
        int q  = (idx >> 2) & 2047;
        int kt = (idx >> 13) & 15;
        int b  = idx >> 17;
        const int* mp = mask + ((size_t)b * NS + q) * NS + kt * 128 + ks * 32;
        u32 v = 0;
        #pragma unroll
        for (int i = 0; i < 8; ++i) {
            int4 a = *(const int4*)(mp + i * 4);
            v |= (u32)(a.x != 0) << (i * 4)
               | (u32)(a.y != 0) << (i * 4 + 1)
               | (u32)(a.z != 0) << (i * 4 + 2)
               | (u32)(a.w != 0) << (i * 4 + 3);
        }
        pmT[idx] = v;
    } else if (bid < 4096) {
        // ---- K split: fragment-exact per-tile image ----
        int idx = (bid - 2048) * 256 + threadIdx.x;
        int oct = idx & 7;
        int kg  = (idx >> 3) & 2047;
        int bh  = idx >> 14;
        const float* src = K + ((size_t)bh * NS + kg) * ND + oct * 8;
        f32x4 a = *(const f32x4*)src;
        f32x4 b = *(const f32x4*)(src + 4);
        u32 h[8], lo[8];
        cvt_split(a.x,h[0],lo[0]); cvt_split(a.y,h[1],lo[1]);
        cvt_split(a.z,h[2],lo[2]); cvt_split(a.w,h[3],lo[3]);
        cvt_split(b.x,h[4],lo[4]); cvt_split(b.y,h[5],lo[5]);
        cvt_split(b.z,h[6],lo[6]); cvt_split(b.w,h[7],lo[7]);
        union { u32 u[4]; s16x8 s; } H, L;
        #pragma unroll
        for (int e = 0; e < 4; ++e) {
            H.u[e] = h[2*e]  | (h[2*e+1]  << 16);
            L.u[e] = lo[2*e] | (lo[2*e+1] << 16);
        }
        int kt = kg >> 7, key = kg & 127, d_ = oct >> 1, hl = oct & 1;
        size_t base = (size_t)(bh * NT + kt) * 16384;
        size_t frag = (size_t)(((d_ * 2 + hl) * 128) + key) * 8;
        *(s16x8*)(khl + base + frag)        = H.s;
        *(s16x8*)(khl + base + 8192 + frag) = L.s;
    } else if (bid < 6144) {
        // ---- Q split: row-major hi/lo planes ----
        int idx = (bid - 4096) * 256 + threadIdx.x;
        int oct = idx & 7;
        size_t row = (size_t)(idx >> 3);
        const float* src = Q + row * ND + oct * 8;
        f32x4 a = *(const f32x4*)src;
        f32x4 b = *(const f32x4*)(src + 4);
        u32 h[8], lo[8];
        cvt_split(a.x,h[0],lo[0]); cvt_split(a.y,h[1],lo[1]);
        cvt_split(a.z,h[2],lo[2]); cvt_split(a.w,h[3],lo[3]);
        cvt_split(b.x,h[4],lo[4]); cvt_split(b.y,h[5],lo[5]);
        cvt_split(b.z,h[6],lo[6]); cvt_split(b.w,h[7],lo[7]);
        union { u32 u[4]; s16x8 s; } H, L;
        #pragma unroll
        for (int e = 0; e < 4; ++e) {
            H.u[e] = h[2*e]  | (h[2*e+1]  << 16);
            L.u[e] = lo[2*e] | (lo[2*e+1] << 16);
        }
        *(s16x8*)(qhi + row * ND + oct * 8) = H.s;
        *(s16x8*)(qlo + row * ND + oct * 8) = L.s;
    } else {
        // ---- partial zero-fill: 64 KB linear per block, heads 0..ZHEADS-1 ----
        int zb = bid - 6144;                       // 0..2047
        f32x4* base = (f32x4*)p + (size_t)zb * 4096 + threadIdx.x;
        f32x4 z4 = {0.f, 0.f, 0.f, 0.f};
        #pragma unroll
        for (int i = 0; i < 16; ++i)
            __builtin_nontemporal_store(z4, base + i * 256);
    }
}

// ---------------------------------------------------------------------------
// qk8<NZT>: r17 kernel unchanged EXCEPT blocks with bh < ZHEADS skip the
// slab zero-fill (those rows were zeroed by prep). Compute/top-2/record
// numerics bit-identical to r17.
// ---------------------------------------------------------------------------
template<int NZT>
__global__ __launch_bounds__(256, 4)
void qk8_kernel(const short* __restrict__ khl,
                const short* __restrict__ qhi,
                const short* __restrict__ qlo,
                const u32* __restrict__ pmT,
                float* __restrict__ p,
                float4* __restrict__ rec)
{
    const int t  = threadIdx.x;
    const int l  = t & 63;
    const int wv = t >> 6;
    const int hl = l >> 5;
    const int ln = l & 31;
    const int bh = blockIdx.x;      // head (same-head blocks -> same XCD)
    const int b  = bh >> 3;
    const int q0 = blockIdx.y * TQ;
    const int z  = blockIdx.z;      // key-range split
    const int kt0 = z * (NT / NZT);
    constexpr int NIT = NT / NZT;   // tiles per block
    constexpr int ZROWS = TQ / NZT; // zero-slab rows per block

    // contiguous zero slab: rows [q0 + z*ZROWS, +ZROWS), all 2048 cols
    float* slab = p + ((size_t)bh * NS + q0 + z * ZROWS) * NS;
    constexpr int SLAB_F4_PER_IT = ZROWS * NS / 4 / NIT;   // f32x4 per iter
    const bool doZero = (bh >= ZHEADS);    // heads 0..7 zeroed by prep
    const int q = q0 + wv * 32 + ln;       // this lane's q-row

    // ---- Q fragments from pre-split planes ----
    s16x8 qh[4], ql[4];
    {
        const short* qr_h = qhi + ((size_t)bh * NS + q) * ND + hl * 8;
        const short* qr_l = qlo + ((size_t)bh * NS + q) * ND + hl * 8;
        #pragma unroll
        for (int d_ = 0; d_ < 4; ++d_) {
            qh[d_] = *(const s16x8*)(qr_h + d_ * 16);
            ql[d_] = *(const s16x8*)(qr_l + d_ * 16);
        }
    }

    const short* kh_head = khl + (size_t)(bh * NT) * 16384;
    const u32*   mrow    = pmT + (size_t)b * (NT * NS * 4) + (size_t)q * 4;

    uint4 mv = *(const uint4*)(mrow + (size_t)kt0 * (NS * 4));
    float m1 = -1e30f, m2 = -1e30f;
    int   i1 = 0;

    for (int kt = kt0, it = 0; it < NIT; ++kt, ++it) {
        // ---- zero a linear chunk of the slab (skipped for prep-zeroed heads) ----
        if (doZero) {
            f32x4* base = (f32x4*)slab + (size_t)it * SLAB_F4_PER_IT + t;
            f32x4 z4 = {0.f, 0.f, 0.f, 0.f};
            #pragma unroll
            for (int i = 0; i < SLAB_F4_PER_IT / 256; ++i)
                __builtin_nontemporal_store(z4, base + i * 256);
        }

        uint4 mv_n = mv;
        if (it + 1 < NIT)
            mv_n = *(const uint4*)(mrow + (size_t)(kt + 1) * (NS * 4));

        const short* kb = kh_head + (size_t)kt * 16384;
        u32 mwv[4] = { mv.x >> (hl * 4), mv.y >> (hl * 4),
                       mv.z >> (hl * 4), mv.w >> (hl * 4) };

        // tree top-2: exact m1/m2, duplicate-safe, chain depth ~10
        auto top2 = [&](const f32x16& A, int ks) {
            u32 ws = mwv[ks];
            int kbase = kt * 128 + ks * 32 + hl * 4;
            float v[16];
            #pragma unroll
            for (int r = 0; r < 16; ++r) {
                int bp = (r & 3) + 8 * (r >> 2);        // C-row pattern (m74/m101)
                v[r] = ((ws >> bp) & 1u) ? A[r] : -1e30f;
            }
            float t8[8], t4[4];
            #pragma unroll
            for (int i = 0; i < 8; ++i) t8[i] = fmaxf(v[i], v[i + 8]);
            #pragma unroll
            for (int i = 0; i < 4; ++i) t4[i] = fmaxf(t8[i], t8[i + 4]);
            float M = fmaxf(fmaxf(t4[0], t4[1]), fmaxf(t4[2], t4[3]));

            float w[16]; int ic[16]; int cn[16];
            #pragma unroll
            for (int r = 0; r < 16; ++r) {
                int bp = (r & 3) + 8 * (r >> 2);
                bool eq = (v[r] == M);
                w[r]  = eq ? -1e30f : v[r];
                ic[r] = eq ? (kbase + bp) : 0;
                cn[r] = eq ? 1 : 0;
            }
            float w8[8], w4[4];
            int   o8[8], o4[4], c8[8], c4[4];
            #pragma unroll
            for (int i = 0; i < 8; ++i) {
                w8[i] = fmaxf(w[i], w[i + 8]);
                o8[i] = ic[i] | ic[i + 8];
                c8[i] = cn[i] + cn[i + 8];
            }
            #pragma unroll
            for (int i = 0; i < 4; ++i) {
                w4[i] = fmaxf(w8[i], w8[i + 4]);
                o4[i] = o8[i] | o8[i + 4];
                c4[i] = c8[i] + c8[i + 4];
            }
            float w2  = fmaxf(fmaxf(w4[0], w4[1]), fmaxf(w4[2], w4[3]));
            int   idx = (o4[0] | o4[1]) | (o4[2] | o4[3]);
            int   cnt = (c4[0] + c4[1]) + (c4[2] + c4[3]);
            float m2t = (cnt > 1) ? M : w2;

            bool gt  = M > m1;
            bool eqr = M == m1;
            float nm2 = gt ? fmaxf(m1, m2t) : (eqr ? m1 : fmaxf(m2, M));
            i1 = gt ? idx : i1;
            m1 = fmaxf(m1, M);
            m2 = nm2;
        };

        #pragma unroll
        for (int kp = 0; kp < 2; ++kp) {
            // ---- load ALL 16 fragments first: 16 b128 loads in flight ----
            s16x8 fh0[4], fl0[4], fh1[4], fl1[4];
            #pragma unroll
            for (int d_ = 0; d_ < 4; ++d_) {
                const short* fr = kb + (size_t)((((d_ * 2 + hl) * 128) + kp * 64 + ln) * 8);
                fh0[d_] = *(const s16x8*)fr;
                fl0[d_] = *(const s16x8*)(fr + 8192);
                fh1[d_] = *(const s16x8*)(fr + 256);
                fl1[d_] = *(const s16x8*)(fr + 8192 + 256);
            }

            f32x16 acc0, acc1;
            #pragma unroll
            for (int r = 0; r < 16; ++r) { acc0[r] = 0.f; acc1[r] = 0.f; }
            #pragma unroll
            for (int d_ = 0; d_ < 4; ++d_) {
                // 3-term split: Kh*Qh + Kl*Qh + Kh*Ql
                acc0 = __builtin_amdgcn_mfma_f32_32x32x16_bf16(fh0[d_], qh[d_], acc0, 0,0,0);
                acc1 = __builtin_amdgcn_mfma_f32_32x32x16_bf16(fh1[d_], qh[d_], acc1, 0,0,0);
                acc0 = __builtin_amdgcn_mfma_f32_32x32x16_bf16(fl0[d_], qh[d_], acc0, 0,0,0);
                acc1 = __builtin_amdgcn_mfma_f32_32x32x16_bf16(fl1[d_], qh[d_], acc1, 0,0,0);
                acc0 = __builtin_amdgcn_mfma_f32_32x32x16_bf16(fh0[d_], ql[d_], acc0, 0,0,0);
                acc1 = __builtin_amdgcn_mfma_f32_32x32x16_bf16(fh1[d_], ql[d_], acc1, 0,0,0);
            }
            top2(acc0, kp * 2);
            top2(acc1, kp * 2 + 1);
        }

        mv = mv_n;
    }

    // ---- merge lane halves (disjoint key sets) ----
    {
        float om1 = __shfl_xor(m1, 32, 64);
        float om2 = __shfl_xor(m2, 32, 64);
        int   oi1 = __shfl_xor(i1, 32, 64);
        float nm1, nm2; int ni1;
        if (om1 > m1)      { nm1 = om1; ni1 = oi1; nm2 = fmaxf(om2, m1); }
        else if (om1 < m1) { nm1 = m1;  ni1 = i1;  nm2 = fmaxf(m2, om1); }
        else { nm1 = m1; ni1 = i1; nm2 = (oi1 == i1) ? fmaxf(m2, om2) : m1; }
        m1 = nm1; i1 = ni1; m2 = nm2;
    }

    // ---- emit record for (row, z) ----
    if (l < 32) {
        int row = bh * NS + q0 + wv * 32 + ln;
        rec[(size_t)row * NZT + z] = make_float4(m1, m2, __int_as_float(i1), 0.f);
    }
}

// ---------------------------------------------------------------------------
// finish<NZT>: merge z records (disjoint key ranges), clean test, one-hot p
// write, out = V[argmax], slow-list append. Stream-ordered after qk8.
// ---------------------------------------------------------------------------
template<int NZT>
__global__ __launch_bounds__(256)
void finish_kernel(const float4* __restrict__ rec,
                   const float* __restrict__ V,
                   float* __restrict__ outp, float* __restrict__ p,
                   int* __restrict__ wsl, int wscap)
{
    int u = blockIdx.x * 256 + threadIdx.x;    // NBH*NS*16 units
    int row = u >> 4, c4 = u & 15;
    float4 r0 = rec[(size_t)row * NZT];
    float m1 = r0.x, m2 = r0.y;
    int   i1 = __float_as_int(r0.z);
    #pragma unroll
    for (int zz = 1; zz < NZT; ++zz) {
        float4 rz = rec[(size_t)row * NZT + zz];
        float a = rz.x;
        int   j = __float_as_int(rz.z);
        if (a > m1)      { m2 = fmaxf(rz.y, m1); m1 = a; i1 = j; }
        else if (a < m1) { m2 = fmaxf(m2, a); }
        else             { m2 = m1; }   // disjoint ranges: tie -> gap 0
    }

    float s1 = __expf(m1) * 0.125f;
    float s2 = __expf(m2) * 0.125f;
    bool clean = (m1 > -1e29f) && (s1 < 1e38f) && (s1 - s2 > 15.0f)
                 && (m1 - m2 > 1e-3f);
    int bh = row >> 11;
    if (clean) {
        const float* vr = V + ((size_t)bh * NS + i1) * ND;
        *(f32x4*)(outp + (size_t)row * ND + c4 * 4) = *(const f32x4*)(vr + c4 * 4);
        if (c4 == 0) p[(size_t)row * NS + i1] = 1.0f;
    } else if (c4 == 0 && wscap > 0) {
        int idx = atomicAdd(wsl, 1);
        if (idx < wscap) wsl[1 + idx] = row;
    }
}

// ---------------------------------------------------------------------------
// Exact reference softmax for listed rows (or ALL rows if allrows).
// ---------------------------------------------------------------------------
__global__ __launch_bounds__(256)
void slow_rows_kernel(const float* __restrict__ Q, const float* __restrict__ K,
                      const float* __restrict__ V, const int* __restrict__ mask,
                      float* __restrict__ outp, float* __restrict__ p,
                      const int* __restrict__ wsl, int wscap, int allrows)
{
    __shared__ float qr[ND];
    __shared__ float redm[4], redz[4];
    __shared__ float ol[ND];
    int n;
    if (allrows) n = NBH * NS;
    else { n = wsl[0]; if (n > wscap) n = wscap; }
    const int t = threadIdx.x;
    const int lane = t & 63, w = t >> 6;

    for (int ii = blockIdx.x; ii < n; ii += gridDim.x) {
        int row = allrows ? ii : wsl[1 + ii];
        int bh = row >> 11, qq = row & (NS - 1), b = bh >> 3;
        const float* Qr = Q + (size_t)row * ND;
        const float* Kb = K + (size_t)bh * NS * ND;
        const float* Vb = V + (size_t)bh * NS * ND;
        const int*   mr = mask + (size_t)b * NS * NS + (size_t)qq * NS;

        __syncthreads();
        if (t < 16) ((float4*)qr)[t] = ((const float4*)Qr)[t];
        if (t < ND) ol[t] = 0.f;
        __syncthreads();

        float sc[8];
        int k0 = t * 8;
        #pragma unroll
        for (int i = 0; i < 8; ++i) {
            const float* kr = Kb + (size_t)(k0 + i) * ND;
            float a = 0.f;
            for (int d = 0; d < ND; d += 4) {
                float4 kv = *(const float4*)(kr + d);
                a += qr[d] * kv.x; a += qr[d + 1] * kv.y;
                a += qr[d + 2] * kv.z; a += qr[d + 3] * kv.w;
            }
            sc[i] = mr[k0 + i] ? __expf(a) * 0.125f : -1e9f;
        }
        float m = sc[0];
        #pragma unroll
        for (int i = 1; i < 8; ++i) m = fmaxf(m, sc[i]);
        #pragma unroll
        for (int d = 1; d < 64; d <<= 1) m = fmaxf(m, __shfl_xor(m, d, 64));
        if (lane == 0) redm[w] = m;
        __syncthreads();
        m = fmaxf(fmaxf(redm[0], redm[1]), fmaxf(redm[2], redm[3]));

        float e[8]; float z = 0.f;
        #pragma unroll
        for (int i = 0; i < 8; ++i) { e[i] = __expf(sc[i] - m); z += e[i]; }
        #pragma unroll
        for (int d = 1; d < 64; d <<= 1) z += __shfl_xor(z, d, 64);
        if (lane == 0) redz[w] = z;
        __syncthreads();
        float Z = redz[0] + redz[1] + redz[2] + redz[3];
        float inv = 1.f / Z;

        float* pr = p + (size_t)row * NS + k0;
        float4 o0, o1;
        o0.x = e[0] * inv; o0.y = e[1] * inv; o0.z = e[2] * inv; o0.w = e[3] * inv;
        o1.x = e[4] * inv; o1.y = e[5] * inv; o1.z = e[6] * inv; o1.w = e[7] * inv;
        *(float4*)pr = o0; *(float4*)(pr + 4) = o1;

        #pragma unroll
        for (int i = 0; i < 8; ++i) {
            float pv = e[i] * inv;
            if (pv > 0.f) {
                const float* vr = Vb + (size_t)(k0 + i) * ND;
                for (int d = 0; d < ND; ++d) atomicAdd(&ol[d], pv * vr[d]);
            }
        }
        __syncthreads();
        if (t < ND) outp[(size_t)row * ND + t] = ol[t];
    }
}

extern "C" void kernel_launch(void* const* d_in, const int* in_sizes, int n_in,
                              void* d_out, int out_size, void* d_ws, size_t ws_size,
                              hipStream_t stream)
{
    const float* Q    = (const float*)d_in[0];
    const float* K    = (const float*)d_in[1];
    const float* V    = (const float*)d_in[2];
    const int*   mask = (const int*)d_in[3];
    float* outp = (float*)d_out;
    float* p    = outp + (size_t)NBH * NS * ND;   // p_attn after out

    if (ws_size < WS_NEED2) {
        slow_rows_kernel<<<dim3(4096), 256, 0, stream>>>(Q, K, V, mask, outp, p,
                                                         nullptr, 0, 1);
        return;
    }

    u32* pmT   = (u32*)d_ws;
    int* wsl   = (int*)((char*)d_ws + PM_BYTES);
    int wscap  = (int)(WSL_BYTES / 4 - 1);
    short* khl = (short*)((char*)d_ws + KHL_OFF);
    short* qhi = (short*)((char*)d_ws + QHI_OFF);
    short* qlo = (short*)((char*)d_ws + QLO_OFF);
    float4* rec = (float4*)((char*)d_ws + REC_OFF);

    // 8192 blocks: 2048 mask + 2048 Ksplit + 2048 Qsplit + 2048 p-zero (heads 0-7)
    prep_kernel<<<dim3(8192), 256, 0, stream>>>(mask, pmT, K, khl, Q, qhi, qlo,
                                                wsl, p);

    if (ws_size >= WS_NEED4) {
        dim3 grid(NBH, NS / TQ, 4);   // 2048 blocks
        qk8_kernel<4><<<grid, 256, 0, stream>>>(khl, qhi, qlo, pmT, p, rec);
        finish_kernel<4><<<dim3(NBH * NS * 16 / 256), 256, 0, stream>>>(
            rec, V, outp, p, wsl, wscap);
    } else {
        dim3 grid(NBH, NS / TQ, 2);   // 1024 blocks
        qk8_kernel<2><<<grid, 256, 0, stream>>>(khl, qhi, qlo, pmT, p, rec);
        finish_kernel<2><<<dim3(NBH * NS * 16 / 256), 256, 0, stream>>>(
            rec, V, outp, p, wsl, wscap);
    }
    slow_rows_kernel<<<dim3(128), 256, 0, stream>>>(Q, K, V, mask, outp, p,
                                                    wsl, wscap, 0);
}

// Round 19
// 163.258 us; speedup vs baseline: 1.0441x; 1.0441x over previous
//
#include <hip/hip_runtime.h>

// Problem: B=4, H=8, S=2048, D=64
// out  = [B*H*S*D]  floats   (first 4,194,304 of d_out)
// p    = [B*H*S*S]  floats   (next 134,217,728 of d_out)
#define NB 4
#define NH 8
#define NS 2048
#define ND 64
#define NBH (NB * NH)

typedef float f32x4  __attribute__((ext_vector_type(4)));
typedef float f32x16 __attribute__((ext_vector_type(16)));
typedef short s16x8  __attribute__((ext_vector_type(8)));
typedef unsigned int u32;

constexpr int TQ = 128;   // q rows per block
constexpr int TK = 128;   // keys per tile
constexpr int NT = NS / TK;

// workspace layout
constexpr size_t PM_BYTES  = (size_t)NB * NS * (NS / 8);        // 2 MiB tile-major mask
constexpr size_t WSL_BYTES = 1 << 20;                           // 1 MiB row list
constexpr size_t KHL_OFF   = PM_BYTES + WSL_BYTES;
constexpr size_t KHL_BYTES = (size_t)NBH * NT * 32768;          // 16.78 MB hi+lo tiles
constexpr size_t QHI_OFF   = KHL_OFF + KHL_BYTES;
constexpr size_t QP_BYTES  = (size_t)NBH * NS * ND * 2;         // 8.39 MB per plane
constexpr size_t QLO_OFF   = QHI_OFF + QP_BYTES;
constexpr size_t REC_OFF   = QLO_OFF + QP_BYTES;
constexpr size_t REC4_BYTES= (size_t)NBH * NS * 4 * 16;         // 4 MB (NZ=4)
constexpr size_t REC2_BYTES= (size_t)NBH * NS * 2 * 16;         // 2 MB (NZ=2)
constexpr size_t WS_NEED4  = REC_OFF + REC4_BYTES;              // ~40.7 MB
constexpr size_t WS_NEED2  = REC_OFF + REC2_BYTES;              // ~38.7 MB

// f32 -> bf16 RNE bits
__device__ __forceinline__ u32 bf16_rne(u32 u) {
    return (u + 0x7FFFu + ((u >> 16) & 1u)) >> 16;
}
__device__ __forceinline__ void cvt_split(float x, u32 &hi, u32 &lo) {
    u32 h = bf16_rne(__float_as_uint(x));
    float hf = __uint_as_float(h << 16);
    lo = bf16_rne(__float_as_uint(x - hf));
    hi = h;
}

// ---------------------------------------------------------------------------
// prep: fused {mask pack (tile-major), K split, Q split, wsl reset}.
// (r18's prep-side zero-fill reverted: prep's HBM pipe is saturated by reads;
// adding writes there lengthened prep more than it shortened qk.)
// ---------------------------------------------------------------------------
__global__ __launch_bounds__(256)
void prep_kernel(const int* __restrict__ mask, u32* __restrict__ pmT,
                 const float* __restrict__ K, short* __restrict__ khl,
                 const float* __restrict__ Q, short* __restrict__ qhi,
                 short* __restrict__ qlo, int* __restrict__ wsl)
{
    const int bid = blockIdx.x;
    if (bid == 0 && threadIdx.x == 0) wsl[0] = 0;

    if (bid < 2048) {
        // ---- tile-major packed mask: word idx = ((b*16+kt)*2048+q)*4+ks ----
        int idx = bid * 256 + threadIdx.x;
        int ks = idx & 3;
        int q  = (idx >> 2) & 2047;
        int kt = (idx >> 13) & 15;
        int b  = idx >> 17;
        const int* mp = mask + ((size_t)b * NS + q) * NS + kt * 128 + ks * 32;
        u32 v = 0;
        #pragma unroll
        for (int i = 0; i < 8; ++i) {
            int4 a = *(const int4*)(mp + i * 4);
            v |= (u32)(a.x != 0) << (i * 4)
               | (u32)(a.y != 0) << (i * 4 + 1)
               | (u32)(a.z != 0) << (i * 4 + 2)
               | (u32)(a.w != 0) << (i * 4 + 3);
        }
        pmT[idx] = v;
    } else if (bid < 4096) {
        // ---- K split: fragment-exact per-tile image ----
        int idx = (bid - 2048) * 256 + threadIdx.x;
        int oct = idx & 7;
        int kg  = (idx >> 3) & 2047;
        int bh  = idx >> 14;
        const float* src = K + ((size_t)bh * NS + kg) * ND + oct * 8;
        f32x4 a = *(const f32x4*)src;
        f32x4 b = *(const f32x4*)(src + 4);
        u32 h[8], lo[8];
        cvt_split(a.x,h[0],lo[0]); cvt_split(a.y,h[1],lo[1]);
        cvt_split(a.z,h[2],lo[2]); cvt_split(a.w,h[3],lo[3]);
        cvt_split(b.x,h[4],lo[4]); cvt_split(b.y,h[5],lo[5]);
        cvt_split(b.z,h[6],lo[6]); cvt_split(b.w,h[7],lo[7]);
        union { u32 u[4]; s16x8 s; } H, L;
        #pragma unroll
        for (int e = 0; e < 4; ++e) {
            H.u[e] = h[2*e]  | (h[2*e+1]  << 16);
            L.u[e] = lo[2*e] | (lo[2*e+1] << 16);
        }
        int kt = kg >> 7, key = kg & 127, d_ = oct >> 1, hl = oct & 1;
        size_t base = (size_t)(bh * NT + kt) * 16384;
        size_t frag = (size_t)(((d_ * 2 + hl) * 128) + key) * 8;
        *(s16x8*)(khl + base + frag)        = H.s;
        *(s16x8*)(khl + base + 8192 + frag) = L.s;
    } else {
        // ---- Q split: row-major hi/lo planes ----
        int idx = (bid - 4096) * 256 + threadIdx.x;
        int oct = idx & 7;
        size_t row = (size_t)(idx >> 3);
        const float* src = Q + row * ND + oct * 8;
        f32x4 a = *(const f32x4*)src;
        f32x4 b = *(const f32x4*)(src + 4);
        u32 h[8], lo[8];
        cvt_split(a.x,h[0],lo[0]); cvt_split(a.y,h[1],lo[1]);
        cvt_split(a.z,h[2],lo[2]); cvt_split(a.w,h[3],lo[3]);
        cvt_split(b.x,h[4],lo[4]); cvt_split(b.y,h[5],lo[5]);
        cvt_split(b.z,h[6],lo[6]); cvt_split(b.w,h[7],lo[7]);
        union { u32 u[4]; s16x8 s; } H, L;
        #pragma unroll
        for (int e = 0; e < 4; ++e) {
            H.u[e] = h[2*e]  | (h[2*e+1]  << 16);
            L.u[e] = lo[2*e] | (lo[2*e+1] << 16);
        }
        *(s16x8*)(qhi + row * ND + oct * 8) = H.s;
        *(s16x8*)(qlo + row * ND + oct * 8) = L.s;
    }
}

// ---------------------------------------------------------------------------
// qk8<NZT>: r17 kernel (best measured config, 163.4 us total). In-block
// {slab zeros <-> compute} alternation, batched 16-fragment loads, tree
// top-2. Numerics bit-identical to rounds 4-17.
// ---------------------------------------------------------------------------
template<int NZT>
__global__ __launch_bounds__(256, 4)
void qk8_kernel(const short* __restrict__ khl,
                const short* __restrict__ qhi,
                const short* __restrict__ qlo,
                const u32* __restrict__ pmT,
                float* __restrict__ p,
                float4* __restrict__ rec)
{
    const int t  = threadIdx.x;
    const int l  = t & 63;
    const int wv = t >> 6;
    const int hl = l >> 5;
    const int ln = l & 31;
    const int bh = blockIdx.x;      // head (same-head blocks -> same XCD)
    const int b  = bh >> 3;
    const int q0 = blockIdx.y * TQ;
    const int z  = blockIdx.z;      // key-range split
    const int kt0 = z * (NT / NZT);
    constexpr int NIT = NT / NZT;   // tiles per block
    constexpr int ZROWS = TQ / NZT; // zero-slab rows per block

    // contiguous zero slab: rows [q0 + z*ZROWS, +ZROWS), all 2048 cols
    float* slab = p + ((size_t)bh * NS + q0 + z * ZROWS) * NS;
    constexpr int SLAB_F4_PER_IT = ZROWS * NS / 4 / NIT;   // f32x4 per iter
    const int q = q0 + wv * 32 + ln;       // this lane's q-row

    // ---- Q fragments from pre-split planes ----
    s16x8 qh[4], ql[4];
    {
        const short* qr_h = qhi + ((size_t)bh * NS + q) * ND + hl * 8;
        const short* qr_l = qlo + ((size_t)bh * NS + q) * ND + hl * 8;
        #pragma unroll
        for (int d_ = 0; d_ < 4; ++d_) {
            qh[d_] = *(const s16x8*)(qr_h + d_ * 16);
            ql[d_] = *(const s16x8*)(qr_l + d_ * 16);
        }
    }

    const short* kh_head = khl + (size_t)(bh * NT) * 16384;
    const u32*   mrow    = pmT + (size_t)b * (NT * NS * 4) + (size_t)q * 4;

    uint4 mv = *(const uint4*)(mrow + (size_t)kt0 * (NS * 4));
    float m1 = -1e30f, m2 = -1e30f;
    int   i1 = 0;

    for (int kt = kt0, it = 0; it < NIT; ++kt, ++it) {
        // ---- zero a linear chunk of the slab (1 KB/wave bursts) ----
        {
            f32x4* base = (f32x4*)slab + (size_t)it * SLAB_F4_PER_IT + t;
            f32x4 z4 = {0.f, 0.f, 0.f, 0.f};
            #pragma unroll
            for (int i = 0; i < SLAB_F4_PER_IT / 256; ++i)
                __builtin_nontemporal_store(z4, base + i * 256);
        }

        uint4 mv_n = mv;
        if (it + 1 < NIT)
            mv_n = *(const uint4*)(mrow + (size_t)(kt + 1) * (NS * 4));

        const short* kb = kh_head + (size_t)kt * 16384;
        u32 mwv[4] = { mv.x >> (hl * 4), mv.y >> (hl * 4),
                       mv.z >> (hl * 4), mv.w >> (hl * 4) };

        // tree top-2: exact m1/m2, duplicate-safe, chain depth ~10
        auto top2 = [&](const f32x16& A, int ks) {
            u32 ws = mwv[ks];
            int kbase = kt * 128 + ks * 32 + hl * 4;
            float v[16];
            #pragma unroll
            for (int r = 0; r < 16; ++r) {
                int bp = (r & 3) + 8 * (r >> 2);        // C-row pattern (m74/m101)
                v[r] = ((ws >> bp) & 1u) ? A[r] : -1e30f;
            }
            float t8[8], t4[4];
            #pragma unroll
            for (int i = 0; i < 8; ++i) t8[i] = fmaxf(v[i], v[i + 8]);
            #pragma unroll
            for (int i = 0; i < 4; ++i) t4[i] = fmaxf(t8[i], t8[i + 4]);
            float M = fmaxf(fmaxf(t4[0], t4[1]), fmaxf(t4[2], t4[3]));

            float w[16]; int ic[16]; int cn[16];
            #pragma unroll
            for (int r = 0; r < 16; ++r) {
                int bp = (r & 3) + 8 * (r >> 2);
                bool eq = (v[r] == M);
                w[r]  = eq ? -1e30f : v[r];
                ic[r] = eq ? (kbase + bp) : 0;
                cn[r] = eq ? 1 : 0;
            }
            float w8[8], w4[4];
            int   o8[8], o4[4], c8[8], c4[4];
            #pragma unroll
            for (int i = 0; i < 8; ++i) {
                w8[i] = fmaxf(w[i], w[i + 8]);
                o8[i] = ic[i] | ic[i + 8];
                c8[i] = cn[i] + cn[i + 8];
            }
            #pragma unroll
            for (int i = 0; i < 4; ++i) {
                w4[i] = fmaxf(w8[i], w8[i + 4]);
                o4[i] = o8[i] | o8[i + 4];
                c4[i] = c8[i] + c8[i + 4];
            }
            float w2  = fmaxf(fmaxf(w4[0], w4[1]), fmaxf(w4[2], w4[3]));
            int   idx = (o4[0] | o4[1]) | (o4[2] | o4[3]);
            int   cnt = (c4[0] + c4[1]) + (c4[2] + c4[3]);
            float m2t = (cnt > 1) ? M : w2;

            bool gt  = M > m1;
            bool eqr = M == m1;
            float nm2 = gt ? fmaxf(m1, m2t) : (eqr ? m1 : fmaxf(m2, M));
            i1 = gt ? idx : i1;
            m1 = fmaxf(m1, M);
            m2 = nm2;
        };

        #pragma unroll
        for (int kp = 0; kp < 2; ++kp) {
            // ---- load ALL 16 fragments first: 16 b128 loads in flight ----
            s16x8 fh0[4], fl0[4], fh1[4], fl1[4];
            #pragma unroll
            for (int d_ = 0; d_ < 4; ++d_) {
                const short* fr = kb + (size_t)((((d_ * 2 + hl) * 128) + kp * 64 + ln) * 8);
                fh0[d_] = *(const s16x8*)fr;
                fl0[d_] = *(const s16x8*)(fr + 8192);
                fh1[d_] = *(const s16x8*)(fr + 256);
                fl1[d_] = *(const s16x8*)(fr + 8192 + 256);
            }

            f32x16 acc0, acc1;
            #pragma unroll
            for (int r = 0; r < 16; ++r) { acc0[r] = 0.f; acc1[r] = 0.f; }
            #pragma unroll
            for (int d_ = 0; d_ < 4; ++d_) {
                // 3-term split: Kh*Qh + Kl*Qh + Kh*Ql
                acc0 = __builtin_amdgcn_mfma_f32_32x32x16_bf16(fh0[d_], qh[d_], acc0, 0,0,0);
                acc1 = __builtin_amdgcn_mfma_f32_32x32x16_bf16(fh1[d_], qh[d_], acc1, 0,0,0);
                acc0 = __builtin_amdgcn_mfma_f32_32x32x16_bf16(fl0[d_], qh[d_], acc0, 0,0,0);
                acc1 = __builtin_amdgcn_mfma_f32_32x32x16_bf16(fl1[d_], qh[d_], acc1, 0,0,0);
                acc0 = __builtin_amdgcn_mfma_f32_32x32x16_bf16(fh0[d_], ql[d_], acc0, 0,0,0);
                acc1 = __builtin_amdgcn_mfma_f32_32x32x16_bf16(fh1[d_], ql[d_], acc1, 0,0,0);
            }
            top2(acc0, kp * 2);
            top2(acc1, kp * 2 + 1);
        }

        mv = mv_n;
    }

    // ---- merge lane halves (disjoint key sets) ----
    {
        float om1 = __shfl_xor(m1, 32, 64);
        float om2 = __shfl_xor(m2, 32, 64);
        int   oi1 = __shfl_xor(i1, 32, 64);
        float nm1, nm2; int ni1;
        if (om1 > m1)      { nm1 = om1; ni1 = oi1; nm2 = fmaxf(om2, m1); }
        else if (om1 < m1) { nm1 = m1;  ni1 = i1;  nm2 = fmaxf(m2, om1); }
        else { nm1 = m1; ni1 = i1; nm2 = (oi1 == i1) ? fmaxf(m2, om2) : m1; }
        m1 = nm1; i1 = ni1; m2 = nm2;
    }

    // ---- emit record for (row, z) ----
    if (l < 32) {
        int row = bh * NS + q0 + wv * 32 + ln;
        rec[(size_t)row * NZT + z] = make_float4(m1, m2, __int_as_float(i1), 0.f);
    }
}

// ---------------------------------------------------------------------------
// finish<NZT>: merge z records (disjoint key ranges), clean test, one-hot p
// write, out = V[argmax], slow-list append. Stream-ordered after qk8.
// ---------------------------------------------------------------------------
template<int NZT>
__global__ __launch_bounds__(256)
void finish_kernel(const float4* __restrict__ rec,
                   const float* __restrict__ V,
                   float* __restrict__ outp, float* __restrict__ p,
                   int* __restrict__ wsl, int wscap)
{
    int u = blockIdx.x * 256 + threadIdx.x;    // NBH*NS*16 units
    int row = u >> 4, c4 = u & 15;
    float4 r0 = rec[(size_t)row * NZT];
    float m1 = r0.x, m2 = r0.y;
    int   i1 = __float_as_int(r0.z);
    #pragma unroll
    for (int zz = 1; zz < NZT; ++zz) {
        float4 rz = rec[(size_t)row * NZT + zz];
        float a = rz.x;
        int   j = __float_as_int(rz.z);
        if (a > m1)      { m2 = fmaxf(rz.y, m1); m1 = a; i1 = j; }
        else if (a < m1) { m2 = fmaxf(m2, a); }
        else             { m2 = m1; }   // disjoint ranges: tie -> gap 0
    }

    float s1 = __expf(m1) * 0.125f;
    float s2 = __expf(m2) * 0.125f;
    bool clean = (m1 > -1e29f) && (s1 < 1e38f) && (s1 - s2 > 15.0f)
                 && (m1 - m2 > 1e-3f);
    int bh = row >> 11;
    if (clean) {
        const float* vr = V + ((size_t)bh * NS + i1) * ND;
        *(f32x4*)(outp + (size_t)row * ND + c4 * 4) = *(const f32x4*)(vr + c4 * 4);
        if (c4 == 0) p[(size_t)row * NS + i1] = 1.0f;
    } else if (c4 == 0 && wscap > 0) {
        int idx = atomicAdd(wsl, 1);
        if (idx < wscap) wsl[1 + idx] = row;
    }
}

// ---------------------------------------------------------------------------
// Exact reference softmax for listed rows (or ALL rows if allrows).
// ---------------------------------------------------------------------------
__global__ __launch_bounds__(256)
void slow_rows_kernel(const float* __restrict__ Q, const float* __restrict__ K,
                      const float* __restrict__ V, const int* __restrict__ mask,
                      float* __restrict__ outp, float* __restrict__ p,
                      const int* __restrict__ wsl, int wscap, int allrows)
{
    __shared__ float qr[ND];
    __shared__ float redm[4], redz[4];
    __shared__ float ol[ND];
    int n;
    if (allrows) n = NBH * NS;
    else { n = wsl[0]; if (n > wscap) n = wscap; }
    const int t = threadIdx.x;
    const int lane = t & 63, w = t >> 6;

    for (int ii = blockIdx.x; ii < n; ii += gridDim.x) {
        int row = allrows ? ii : wsl[1 + ii];
        int bh = row >> 11, qq = row & (NS - 1), b = bh >> 3;
        const float* Qr = Q + (size_t)row * ND;
        const float* Kb = K + (size_t)bh * NS * ND;
        const float* Vb = V + (size_t)bh * NS * ND;
        const int*   mr = mask + (size_t)b * NS * NS + (size_t)qq * NS;

        __syncthreads();
        if (t < 16) ((float4*)qr)[t] = ((const float4*)Qr)[t];
        if (t < ND) ol[t] = 0.f;
        __syncthreads();

        float sc[8];
        int k0 = t * 8;
        #pragma unroll
        for (int i = 0; i < 8; ++i) {
            const float* kr = Kb + (size_t)(k0 + i) * ND;
            float a = 0.f;
            for (int d = 0; d < ND; d += 4) {
                float4 kv = *(const float4*)(kr + d);
                a += qr[d] * kv.x; a += qr[d + 1] * kv.y;
                a += qr[d + 2] * kv.z; a += qr[d + 3] * kv.w;
            }
            sc[i] = mr[k0 + i] ? __expf(a) * 0.125f : -1e9f;
        }
        float m = sc[0];
        #pragma unroll
        for (int i = 1; i < 8; ++i) m = fmaxf(m, sc[i]);
        #pragma unroll
        for (int d = 1; d < 64; d <<= 1) m = fmaxf(m, __shfl_xor(m, d, 64));
        if (lane == 0) redm[w] = m;
        __syncthreads();
        m = fmaxf(fmaxf(redm[0], redm[1]), fmaxf(redm[2], redm[3]));

        float e[8]; float z = 0.f;
        #pragma unroll
        for (int i = 0; i < 8; ++i) { e[i] = __expf(sc[i] - m); z += e[i]; }
        #pragma unroll
        for (int d = 1; d < 64; d <<= 1) z += __shfl_xor(z, d, 64);
        if (lane == 0) redz[w] = z;
        __syncthreads();
        float Z = redz[0] + redz[1] + redz[2] + redz[3];
        float inv = 1.f / Z;

        float* pr = p + (size_t)row * NS + k0;
        float4 o0, o1;
        o0.x = e[0] * inv; o0.y = e[1] * inv; o0.z = e[2] * inv; o0.w = e[3] * inv;
        o1.x = e[4] * inv; o1.y = e[5] * inv; o1.z = e[6] * inv; o1.w = e[7] * inv;
        *(float4*)pr = o0; *(float4*)(pr + 4) = o1;

        #pragma unroll
        for (int i = 0; i < 8; ++i) {
            float pv = e[i] * inv;
            if (pv > 0.f) {
                const float* vr = Vb + (size_t)(k0 + i) * ND;
                for (int d = 0; d < ND; ++d) atomicAdd(&ol[d], pv * vr[d]);
            }
        }
        __syncthreads();
        if (t < ND) outp[(size_t)row * ND + t] = ol[t];
    }
}

extern "C" void kernel_launch(void* const* d_in, const int* in_sizes, int n_in,
                              void* d_out, int out_size, void* d_ws, size_t ws_size,
                              hipStream_t stream)
{
    const float* Q    = (const float*)d_in[0];
    const float* K    = (const float*)d_in[1];
    const float* V    = (const float*)d_in[2];
    const int*   mask = (const int*)d_in[3];
    float* outp = (float*)d_out;
    float* p    = outp + (size_t)NBH * NS * ND;   // p_attn after out

    if (ws_size < WS_NEED2) {
        slow_rows_kernel<<<dim3(4096), 256, 0, stream>>>(Q, K, V, mask, outp, p,
                                                         nullptr, 0, 1);
        return;
    }

    u32* pmT   = (u32*)d_ws;
    int* wsl   = (int*)((char*)d_ws + PM_BYTES);
    int wscap  = (int)(WSL_BYTES / 4 - 1);
    short* khl = (short*)((char*)d_ws + KHL_OFF);
    short* qhi = (short*)((char*)d_ws + QHI_OFF);
    short* qlo = (short*)((char*)d_ws + QLO_OFF);
    float4* rec = (float4*)((char*)d_ws + REC_OFF);

    prep_kernel<<<dim3(6144), 256, 0, stream>>>(mask, pmT, K, khl, Q, qhi, qlo, wsl);

    if (ws_size >= WS_NEED4) {
        dim3 grid(NBH, NS / TQ, 4);   // 2048 blocks
        qk8_kernel<4><<<grid, 256, 0, stream>>>(khl, qhi, qlo, pmT, p, rec);
        finish_kernel<4><<<dim3(NBH * NS * 16 / 256), 256, 0, stream>>>(
            rec, V, outp, p, wsl, wscap);
    } else {
        dim3 grid(NBH, NS / TQ, 2);   // 1024 blocks
        qk8_kernel<2><<<grid, 256, 0, stream>>>(khl, qhi, qlo, pmT, p, rec);
        finish_kernel<2><<<dim3(NBH * NS * 16 / 256), 256, 0, stream>>>(
            rec, V, outp, p, wsl, wscap);
    }
    slow_rows_kernel<<<dim3(512), 256, 0, stream>>>(Q, K, V, mask, outp, p,
                                                    wsl, wscap, 0);
}